// Round 1
// baseline (827.836 us; speedup 1.0000x reference)
//
#include <hip/hip_runtime.h>

// Problem constants
constexpr int kB  = 16;
constexpr int kLM = 1024;
constexpr int kLX = 1024;
constexpr int kD  = 768;

// ---------------------------------------------------------------------------
// Kernel 1: G[b] = x[b]^T @ x[b]   (D x D, K = LX)
// Both operands are loaded K-row-contiguous (NT-style): no transpose needed.
// 64x64 block tile, KT=16, 256 threads, 4x4 micro-tile per thread.
// ---------------------------------------------------------------------------
__global__ __launch_bounds__(256) void gram_kernel(const float* __restrict__ x,
                                                   float* __restrict__ G) {
    __shared__ float As[16][68];   // pad to 68 (17 float4) to break store conflicts
    __shared__ float Bs[16][68];
    const int b  = blockIdx.z;
    const int i0 = blockIdx.x * 64;
    const int j0 = blockIdx.y * 64;
    const int tid = threadIdx.x;
    const int lr = tid >> 4;           // 0..15  (K row within tile)
    const int lc = (tid & 15) << 2;    // 0..60  (col, float4)
    const int tx = tid & 15;
    const int ty = tid >> 4;
    const float* xb = x + (size_t)b * kLX * kD;

    float acc[4][4] = {};
    for (int k0 = 0; k0 < kLX; k0 += 16) {
        const float4 av = *(const float4*)(xb + (size_t)(k0 + lr) * kD + i0 + lc);
        const float4 bv = *(const float4*)(xb + (size_t)(k0 + lr) * kD + j0 + lc);
        *(float4*)&As[lr][lc] = av;
        *(float4*)&Bs[lr][lc] = bv;
        __syncthreads();
#pragma unroll
        for (int k = 0; k < 16; ++k) {
            float ar[4], br[4];
#pragma unroll
            for (int i = 0; i < 4; ++i) ar[i] = As[k][ty * 4 + i];
#pragma unroll
            for (int j = 0; j < 4; ++j) br[j] = Bs[k][tx * 4 + j];
#pragma unroll
            for (int i = 0; i < 4; ++i)
#pragma unroll
                for (int j = 0; j < 4; ++j) acc[i][j] += ar[i] * br[j];
        }
        __syncthreads();
    }
    float* Gb = G + (size_t)b * kD * kD;
#pragma unroll
    for (int i = 0; i < 4; ++i) {
        float4 v = make_float4(acc[i][0], acc[i][1], acc[i][2], acc[i][3]);
        *(float4*)(Gb + (size_t)(i0 + ty * 4 + i) * kD + j0 + tx * 4) = v;
    }
}

// ---------------------------------------------------------------------------
// Kernel 2/3: C[b] = A[b?] @ B[b]   (row-major NN GEMM, K = N = 768)
// A is loaded with transpose into LDS (stride 65 to break bank conflicts).
// ---------------------------------------------------------------------------
__global__ __launch_bounds__(256) void gemm_nn_kernel(
    const float* __restrict__ A, const float* __restrict__ B, float* __restrict__ C,
    int K, int N, long strideA, long strideB, long strideC) {
    __shared__ float As[16][65];   // [k][i], transposed store
    __shared__ float Bs[16][68];   // [k][j], direct float4 store
    const int b  = blockIdx.z;
    const int i0 = blockIdx.x * 64;
    const int j0 = blockIdx.y * 64;
    const int tid = threadIdx.x;
    const float* Ab = A + (size_t)b * strideA;
    const float* Bb = B + (size_t)b * strideB;
    float* Cb = C + (size_t)b * strideC;

    const int ar = tid >> 2;           // 0..63 (row within A tile)
    const int ac = (tid & 3) << 2;     // 0,4,8,12 (k within A tile, float4)
    const int brow = tid >> 4;         // 0..15
    const int bcol = (tid & 15) << 2;  // 0..60
    const int tx = tid & 15;
    const int ty = tid >> 4;

    float acc[4][4] = {};
    for (int k0 = 0; k0 < K; k0 += 16) {
        const float4 av = *(const float4*)(Ab + (size_t)(i0 + ar) * K + k0 + ac);
        const float4 bv = *(const float4*)(Bb + (size_t)(k0 + brow) * N + j0 + bcol);
        As[ac + 0][ar] = av.x;
        As[ac + 1][ar] = av.y;
        As[ac + 2][ar] = av.z;
        As[ac + 3][ar] = av.w;
        *(float4*)&Bs[brow][bcol] = bv;
        __syncthreads();
#pragma unroll
        for (int k = 0; k < 16; ++k) {
            float areg[4], breg[4];
#pragma unroll
            for (int i = 0; i < 4; ++i) areg[i] = As[k][ty * 4 + i];
#pragma unroll
            for (int j = 0; j < 4; ++j) breg[j] = Bs[k][tx * 4 + j];
#pragma unroll
            for (int i = 0; i < 4; ++i)
#pragma unroll
                for (int j = 0; j < 4; ++j) acc[i][j] += areg[i] * breg[j];
        }
        __syncthreads();
    }
#pragma unroll
    for (int i = 0; i < 4; ++i) {
        float4 v = make_float4(acc[i][0], acc[i][1], acc[i][2], acc[i][3]);
        *(float4*)(Cb + (size_t)(i0 + ty * 4 + i) * N + j0 + tx * 4) = v;
    }
}

// ---------------------------------------------------------------------------
// Kernel 4: beta[b,m] = sum_d (main-A)*w1[d] + (main*A)*w2[d]
// One wave (64 lanes) per row; 4 waves per block.
// ---------------------------------------------------------------------------
__global__ __launch_bounds__(256) void beta_kernel(const float* __restrict__ mainp,
                                                   const float* __restrict__ Aout,
                                                   const float* __restrict__ w,
                                                   float* __restrict__ beta) {
    const int row  = blockIdx.x * 4 + (threadIdx.x >> 6);  // 0 .. B*LM-1
    const int lane = threadIdx.x & 63;
    const float* mr = mainp + (size_t)row * kD;
    const float* ar = Aout + (size_t)row * kD;
    float acc = 0.f;
#pragma unroll
    for (int d = lane; d < kD; d += 64) {
        const float mv = mr[d];
        const float av = ar[d];
        acc += (mv - av) * w[d] + (mv * av) * w[kD + d];
    }
#pragma unroll
    for (int off = 32; off > 0; off >>= 1) acc += __shfl_down(acc, off);
    if (lane == 0) beta[row] = acc;
}

// ---------------------------------------------------------------------------
// Kernel 5: pooled[b, 0:D]   = sum_m beta * (main - A)
//           pooled[b, D:2D]  = sum_m beta * (main * A)
// Block = (b, chunk of 64 rows); 768 threads = one d each; atomicAdd partials.
// ---------------------------------------------------------------------------
__global__ __launch_bounds__(768) void pooled_kernel(const float* __restrict__ mainp,
                                                     const float* __restrict__ Aout,
                                                     const float* __restrict__ beta,
                                                     float* __restrict__ out) {
    const int b  = blockIdx.y;    // 0..15
    const int mc = blockIdx.x;    // 0..15 (chunk of 64 rows)
    const int d  = threadIdx.x;   // 0..767
    const float* mb = mainp + ((size_t)b * kLM + mc * 64) * kD;
    const float* ab = Aout + ((size_t)b * kLM + mc * 64) * kD;
    const float* bb = beta + (size_t)b * kLM + mc * 64;
    float ps = 0.f, pm = 0.f;
#pragma unroll 4
    for (int m = 0; m < 64; ++m) {
        const float be = bb[m];
        const float mv = mb[(size_t)m * kD + d];
        const float av = ab[(size_t)m * kD + d];
        ps += be * (mv - av);
        pm += be * (mv * av);
    }
    atomicAdd(&out[(size_t)b * 2 * kD + d], ps);
    atomicAdd(&out[(size_t)b * 2 * kD + kD + d], pm);
}

extern "C" void kernel_launch(void* const* d_in, const int* in_sizes, int n_in,
                              void* d_out, int out_size, void* d_ws, size_t ws_size,
                              hipStream_t stream) {
    const float* mainp = (const float*)d_in[0];  // (B, LM, D)
    const float* x     = (const float*)d_in[1];  // (B, LX, D)
    const float* W     = (const float*)d_in[2];  // (D, D)
    const float* w     = (const float*)d_in[3];  // (2D, 1)
    float* out = (float*)d_out;                  // (B, 2D)

    float* ws   = (float*)d_ws;
    float* G    = ws;                            // B*D*D
    float* Mm   = G + (size_t)kB * kD * kD;      // B*D*D
    float* Aout = Mm + (size_t)kB * kD * kD;     // B*LM*D
    float* beta = Aout + (size_t)kB * kLM * kD;  // B*LM

    // d_out is poisoned to 0xAA before every launch; pooled_kernel accumulates.
    hipMemsetAsync(out, 0, (size_t)kB * 2 * kD * sizeof(float), stream);

    // G[b] = x[b]^T x[b]
    gram_kernel<<<dim3(kD / 64, kD / 64, kB), 256, 0, stream>>>(x, G);
    // M[b] = W @ G[b]
    gemm_nn_kernel<<<dim3(kD / 64, kD / 64, kB), 256, 0, stream>>>(
        W, G, Mm, kD, kD, 0L, (long)kD * kD, (long)kD * kD);
    // A[b] = main[b] @ M[b]
    gemm_nn_kernel<<<dim3(kLM / 64, kD / 64, kB), 256, 0, stream>>>(
        mainp, Mm, Aout, kD, kD, (long)kLM * kD, (long)kD * kD, (long)kLM * kD);
    // beta
    beta_kernel<<<dim3(kB * kLM / 4), 256, 0, stream>>>(mainp, Aout, w, beta);
    // pooled
    pooled_kernel<<<dim3(kLM / 64, kB), 768, 0, stream>>>(mainp, Aout, beta, out);
}

// Round 2
// 260.760 us; speedup vs baseline: 3.1747x; 3.1747x over previous
//
#include <hip/hip_runtime.h>

constexpr int kB  = 16;
constexpr int kLM = 1024;
constexpr int kLX = 1024;
constexpr int kD  = 768;

using short8 = __attribute__((ext_vector_type(8))) short;
using f32x4  = __attribute__((ext_vector_type(4))) float;

__device__ __forceinline__ unsigned short f2bf(float f) {
    unsigned u = __float_as_uint(f);
    u = (u + 0x7FFF + ((u >> 16) & 1)) >> 16;   // RNE
    return (unsigned short)u;
}
__device__ __forceinline__ float bf2f(unsigned short h) {
    return __uint_as_float(((unsigned)h) << 16);
}

// ---------------------------------------------------------------------------
// Transpose + convert: xT[b][d][l] = bf16(x[b][l][d])
// 64x64 tiles through LDS (stride 65 breaks conflicts).
// ---------------------------------------------------------------------------
__global__ __launch_bounds__(256) void transpose_cvt_kernel(
    const float* __restrict__ x, unsigned short* __restrict__ xT) {
    __shared__ float tile[64][65];
    const int b  = blockIdx.z;
    const int l0 = blockIdx.x * 64;   // LX
    const int d0 = blockIdx.y * 64;   // D
    const int t  = threadIdx.x;
    const int tx = t & 15, ty = t >> 4;   // tx 0..15, ty 0..15
    const float* xb = x + ((size_t)b * kLX + l0) * kD + d0;
#pragma unroll
    for (int p = 0; p < 4; ++p) {
        int r = p * 16 + ty;
        float4 v = *(const float4*)(xb + (size_t)r * kD + tx * 4);
        *(float4*)&tile[r][tx * 4] = v;
    }
    __syncthreads();
    unsigned short* xTb = xT + ((size_t)b * kD + d0) * kLX + l0;
#pragma unroll
    for (int p = 0; p < 4; ++p) {
        int dr = p * 16 + ty;    // output row (d)
        ushort4 o;
        o.x = f2bf(tile[tx * 4 + 0][dr]);
        o.y = f2bf(tile[tx * 4 + 1][dr]);
        o.z = f2bf(tile[tx * 4 + 2][dr]);
        o.w = f2bf(tile[tx * 4 + 3][dr]);
        *(ushort4*)(xTb + (size_t)dr * kLX + tx * 4) = o;
    }
}

// ---------------------------------------------------------------------------
// Elementwise fp32 -> bf16 (4 elements / thread)
// ---------------------------------------------------------------------------
__global__ __launch_bounds__(256) void cvt_bf16_kernel(
    const float* __restrict__ in, unsigned short* __restrict__ out, int n4) {
    int i = blockIdx.x * blockDim.x + threadIdx.x;
    if (i < n4) {
        float4 v = ((const float4*)in)[i];
        ushort4 o;
        o.x = f2bf(v.x); o.y = f2bf(v.y); o.z = f2bf(v.z); o.w = f2bf(v.w);
        ((ushort4*)out)[i] = o;
    }
}

// ---------------------------------------------------------------------------
// NT bf16 MFMA GEMM: C[i][j] = sum_k A[i][k] * B[j][k]   (both K-contiguous)
// 128x128 block tile, BK=32, 256 threads (4 waves, 2x2), 4x4 MFMA per wave.
// LDS row stride 40 bf16 (80 B): 16B-aligned b128 reads, only 2-way aliasing.
// ---------------------------------------------------------------------------
constexpr int LDT = 40;
__global__ __launch_bounds__(256) void gemm_nt_bf16_kernel(
    const unsigned short* __restrict__ A, const unsigned short* __restrict__ B,
    unsigned short* __restrict__ C, int M, int N, int K,
    long sA, long sB, long sC) {
    __shared__ unsigned short Asm[128 * LDT];
    __shared__ unsigned short Bsm[128 * LDT];
    const int b  = blockIdx.z;
    const int i0 = blockIdx.x * 128;
    const int j0 = blockIdx.y * 128;
    const int t    = threadIdx.x;
    const int wave = t >> 6, lane = t & 63;
    const int wr = (wave >> 1) * 64, wc = (wave & 1) * 64;
    const int quad = lane >> 4, l15 = lane & 15;

    const unsigned short* Ab = A + (size_t)b * sA + (size_t)i0 * K;
    const unsigned short* Bb = B + (size_t)b * sB + (size_t)j0 * K;

    const int srow = t >> 2;        // 0..63
    const int sseg = t & 3;         // 0..3 (8 bf16 each)

    f32x4 acc[4][4];
    const f32x4 z = {0.f, 0.f, 0.f, 0.f};
#pragma unroll
    for (int i = 0; i < 4; ++i)
#pragma unroll
        for (int j = 0; j < 4; ++j) acc[i][j] = z;

    for (int k0 = 0; k0 < K; k0 += 32) {
        float4 a0 = *(const float4*)(Ab + (size_t)srow * K + k0 + sseg * 8);
        float4 a1 = *(const float4*)(Ab + (size_t)(srow + 64) * K + k0 + sseg * 8);
        float4 b0 = *(const float4*)(Bb + (size_t)srow * K + k0 + sseg * 8);
        float4 b1 = *(const float4*)(Bb + (size_t)(srow + 64) * K + k0 + sseg * 8);
        __syncthreads();   // previous tile's compute done before overwrite
        *(float4*)(Asm + srow * LDT + sseg * 8)        = a0;
        *(float4*)(Asm + (srow + 64) * LDT + sseg * 8) = a1;
        *(float4*)(Bsm + srow * LDT + sseg * 8)        = b0;
        *(float4*)(Bsm + (srow + 64) * LDT + sseg * 8) = b1;
        __syncthreads();
        short8 af[4], bg[4];
#pragma unroll
        for (int i = 0; i < 4; ++i)
            af[i] = *(const short8*)(Asm + (wr + i * 16 + l15) * LDT + quad * 8);
#pragma unroll
        for (int j = 0; j < 4; ++j)
            bg[j] = *(const short8*)(Bsm + (wc + j * 16 + l15) * LDT + quad * 8);
#pragma unroll
        for (int i = 0; i < 4; ++i)
#pragma unroll
            for (int j = 0; j < 4; ++j)
                acc[i][j] = __builtin_amdgcn_mfma_f32_16x16x32_bf16(
                    af[i], bg[j], acc[i][j], 0, 0, 0);
    }

    // C/D layout: col = lane&15, row = quad*4 + reg  [m89/m91 verified]
    unsigned short* Cb = C + (size_t)b * sC + (size_t)(i0 + wr) * N + j0 + wc;
#pragma unroll
    for (int i = 0; i < 4; ++i)
#pragma unroll
        for (int j = 0; j < 4; ++j)
#pragma unroll
            for (int r = 0; r < 4; ++r)
                Cb[(size_t)(i * 16 + quad * 4 + r) * N + j * 16 + l15] =
                    f2bf(acc[i][j][r]);
}

// ---------------------------------------------------------------------------
// Fused beta + pooled:
//   beta_m = sum_d (main-A)*w1 + (main*A)*w2
//   pooled[b] += beta_m * [s_m | m_m]
// Block = (b, 64-row chunk); wave handles 16 rows; lane holds d = seg*64+lane.
// ---------------------------------------------------------------------------
__global__ __launch_bounds__(256) void pool_kernel(
    const float* __restrict__ mainp, const unsigned short* __restrict__ Aout,
    const float* __restrict__ w, float* __restrict__ out) {
    const int b     = blockIdx.y;
    const int chunk = blockIdx.x;           // 16 chunks of 64 rows
    const int wave  = threadIdx.x >> 6, lane = threadIdx.x & 63;
    float w1[12], w2[12], ps[12], pm[12];
#pragma unroll
    for (int s = 0; s < 12; ++s) {
        w1[s] = w[s * 64 + lane];
        w2[s] = w[kD + s * 64 + lane];
        ps[s] = 0.f; pm[s] = 0.f;
    }
    for (int rr = 0; rr < 16; ++rr) {
        const int row = chunk * 64 + rr * 4 + wave;
        const float* mr = mainp + ((size_t)b * kLM + row) * kD;
        const unsigned short* ar = Aout + ((size_t)b * kLM + row) * kD;
        float sv[12], mv[12], acc = 0.f;
#pragma unroll
        for (int s = 0; s < 12; ++s) {
            float m_ = mr[s * 64 + lane];
            float a_ = bf2f(ar[s * 64 + lane]);
            sv[s] = m_ - a_;
            mv[s] = m_ * a_;
            acc += sv[s] * w1[s] + mv[s] * w2[s];
        }
#pragma unroll
        for (int off = 32; off; off >>= 1) acc += __shfl_xor(acc, off);
#pragma unroll
        for (int s = 0; s < 12; ++s) { ps[s] += acc * sv[s]; pm[s] += acc * mv[s]; }
    }
    float* ob = out + (size_t)b * 2 * kD;
#pragma unroll
    for (int s = 0; s < 12; ++s) {
        atomicAdd(&ob[s * 64 + lane], ps[s]);
        atomicAdd(&ob[kD + s * 64 + lane], pm[s]);
    }
}

extern "C" void kernel_launch(void* const* d_in, const int* in_sizes, int n_in,
                              void* d_out, int out_size, void* d_ws, size_t ws_size,
                              hipStream_t stream) {
    const float* mainp = (const float*)d_in[0];  // (B, LM, D)
    const float* x     = (const float*)d_in[1];  // (B, LX, D)
    const float* W     = (const float*)d_in[2];  // (D, D)
    const float* w     = (const float*)d_in[3];  // (2D, 1)
    float* out = (float*)d_out;                  // (B, 2D)

    char* p = (char*)d_ws;
    unsigned short* xT    = (unsigned short*)p; p += (size_t)kB * kD * kLX * 2;
    unsigned short* mainb = (unsigned short*)p; p += (size_t)kB * kLM * kD * 2;
    unsigned short* Wb    = (unsigned short*)p; p += (size_t)kD * kD * 2;
    unsigned short* G     = (unsigned short*)p; p += (size_t)kB * kD * kD * 2;
    unsigned short* Mt    = (unsigned short*)p; p += (size_t)kB * kD * kD * 2;
    unsigned short* Ao    = (unsigned short*)p; p += (size_t)kB * kLM * kD * 2;

    hipMemsetAsync(out, 0, (size_t)kB * 2 * kD * sizeof(float), stream);

    // xT = transpose(x) in bf16
    transpose_cvt_kernel<<<dim3(kLX / 64, kD / 64, kB), 256, 0, stream>>>(x, xT);
    // main, W -> bf16
    {
        int n4 = kB * kLM * kD / 4;
        cvt_bf16_kernel<<<(n4 + 255) / 256, 256, 0, stream>>>(mainp, mainb, n4);
        n4 = kD * kD / 4;
        cvt_bf16_kernel<<<(n4 + 255) / 256, 256, 0, stream>>>(W, Wb, n4);
    }
    // G[b] = xT[b] @ xT[b]^T  (= x^T x, symmetric)
    gemm_nt_bf16_kernel<<<dim3(kD / 128, kD / 128, kB), 256, 0, stream>>>(
        xT, xT, G, kD, kD, kLX, (long)kD * kLX, (long)kD * kLX, (long)kD * kD);
    // Mt[b] = G[b] @ W^T   (= (W G)^T since G symmetric)
    gemm_nt_bf16_kernel<<<dim3(kD / 128, kD / 128, kB), 256, 0, stream>>>(
        G, Wb, Mt, kD, kD, kD, (long)kD * kD, 0L, (long)kD * kD);
    // A[b] = main[b] @ Mt[b]^T
    gemm_nt_bf16_kernel<<<dim3(kLM / 128, kD / 128, kB), 256, 0, stream>>>(
        mainb, Mt, Ao, kLM, kD, kD, (long)kLM * kD, (long)kD * kD, (long)kLM * kD);
    // fused beta + pooled
    pool_kernel<<<dim3(kLM / 64, kB), 256, 0, stream>>>(mainp, Ao, w, out);
}

// Round 3
// 256.141 us; speedup vs baseline: 3.2320x; 1.0180x over previous
//
#include <hip/hip_runtime.h>

constexpr int kB  = 16;
constexpr int kLM = 1024;
constexpr int kLX = 1024;
constexpr int kD  = 768;

using short8 = __attribute__((ext_vector_type(8))) short;
using f32x4  = __attribute__((ext_vector_type(4))) float;

__device__ __forceinline__ unsigned short f2bf(float f) {
    unsigned u = __float_as_uint(f);
    u = (u + 0x7FFF + ((u >> 16) & 1)) >> 16;   // RNE
    return (unsigned short)u;
}
__device__ __forceinline__ float bf2f(unsigned short h) {
    return __uint_as_float(((unsigned)h) << 16);
}

// async 16B global->LDS copy (DMA, no VGPR round-trip). LDS dest must be
// wave-uniform-base + lane*16 — caller guarantees lane-order-contiguous dst.
__device__ __forceinline__ void gl_lds16(const unsigned short* g, unsigned short* l) {
    auto gp = (const __attribute__((address_space(1))) unsigned int*)g;
    auto lp = (__attribute__((address_space(3))) unsigned int*)l;
    __builtin_amdgcn_global_load_lds(gp, lp, 16, 0, 0);
}

// ---------------------------------------------------------------------------
// Transpose + convert: xT[b][d][l] = bf16(x[b][l][d])
// ---------------------------------------------------------------------------
__global__ __launch_bounds__(256) void transpose_cvt_kernel(
    const float* __restrict__ x, unsigned short* __restrict__ xT) {
    __shared__ float tile[64][65];
    const int b  = blockIdx.z;
    const int l0 = blockIdx.x * 64;   // LX
    const int d0 = blockIdx.y * 64;   // D
    const int t  = threadIdx.x;
    const int tx = t & 15, ty = t >> 4;
    const float* xb = x + ((size_t)b * kLX + l0) * kD + d0;
#pragma unroll
    for (int p = 0; p < 4; ++p) {
        int r = p * 16 + ty;
        float4 v = *(const float4*)(xb + (size_t)r * kD + tx * 4);
        *(float4*)&tile[r][tx * 4] = v;
    }
    __syncthreads();
    unsigned short* xTb = xT + ((size_t)b * kD + d0) * kLX + l0;
#pragma unroll
    for (int p = 0; p < 4; ++p) {
        int dr = p * 16 + ty;
        ushort4 o;
        o.x = f2bf(tile[tx * 4 + 0][dr]);
        o.y = f2bf(tile[tx * 4 + 1][dr]);
        o.z = f2bf(tile[tx * 4 + 2][dr]);
        o.w = f2bf(tile[tx * 4 + 3][dr]);
        *(ushort4*)(xTb + (size_t)dr * kLX + tx * 4) = o;
    }
}

__global__ __launch_bounds__(256) void cvt_bf16_kernel(
    const float* __restrict__ in, unsigned short* __restrict__ out, int n4) {
    int i = blockIdx.x * blockDim.x + threadIdx.x;
    if (i < n4) {
        float4 v = ((const float4*)in)[i];
        ushort4 o;
        o.x = f2bf(v.x); o.y = f2bf(v.y); o.z = f2bf(v.z); o.w = f2bf(v.w);
        ((ushort4*)out)[i] = o;
    }
}

// ---------------------------------------------------------------------------
// NT bf16 MFMA GEMM, m97 structure: C[i][j] = sum_k A[i][k]*B[j][k].
// 128x128 tile, BK=32, 256 thr (4 waves 2x2), 16x16x32 MFMA, 4x4 per wave.
// Staging: global_load_lds width=16 into XOR-swizzled chunk layout:
//   LDS chunk p(r,q) = (r>>1)*8 + (((r&1)*4+q) ^ ((r>>1)&7)), chunk = 16B.
// Fragment ds_read_b128: every 8-lane group hits 8 distinct bank-quads.
// ---------------------------------------------------------------------------
__global__ __launch_bounds__(256) void gemm_nt_bf16_kernel(
    const unsigned short* __restrict__ A, const unsigned short* __restrict__ B,
    unsigned short* __restrict__ C, int M, int N, int K,
    long sA, long sB, long sC) {
    __shared__ unsigned short Asm[128 * 32];   // 8 KB, swizzled chunk order
    __shared__ unsigned short Bsm[128 * 32];
    const int b  = blockIdx.z;
    const int i0 = blockIdx.x * 128;
    const int j0 = blockIdx.y * 128;
    const int t    = threadIdx.x;
    const int wave = t >> 6, lane = t & 63;
    const int wr = (wave >> 1) * 64, wc = (wave & 1) * 64;
    const int quad = lane >> 4, l15 = lane & 15;

    const unsigned short* Ab = A + (size_t)b * sA + (size_t)i0 * K;
    const unsigned short* Bb = B + (size_t)b * sB + (size_t)j0 * K;

    // staging: thread handles LDS chunks c0 (pass0) and c1 (pass1) of each tile
    const int c0 = wave * 64 + lane;
    const int c1 = 256 + wave * 64 + lane;
    // inverse swizzle: LDS chunk c -> global (row, kseg)
    auto chunk_off = [&](int c) -> size_t {
        int sr = c >> 3, s = c & 7;
        int tt = s ^ (sr & 7);
        int r  = sr * 2 + (tt >> 2);
        int q  = tt & 3;
        return (size_t)r * K + q * 8;
    };
    const size_t off0 = chunk_off(c0);
    const size_t off1 = chunk_off(c1);

    // fragment read base: global (row = wrow + i*16 + l15, kseg = quad)
    const int sfr = ((l15 & 1) * 4 + quad) ^ ((l15 >> 1) & 7);
    const unsigned short* aP = Asm + ((wr >> 1) * 64 + (l15 >> 1) * 64 + sfr * 8);
    const unsigned short* bP = Bsm + ((wc >> 1) * 64 + (l15 >> 1) * 64 + sfr * 8);

    f32x4 acc[4][4];
    const f32x4 z = {0.f, 0.f, 0.f, 0.f};
#pragma unroll
    for (int i = 0; i < 4; ++i)
#pragma unroll
        for (int j = 0; j < 4; ++j) acc[i][j] = z;

    for (int k0 = 0; k0 < K; k0 += 32) {
        __syncthreads();   // all waves done reading previous tile
        gl_lds16(Ab + off0 + k0, Asm + c0 * 8);
        gl_lds16(Ab + off1 + k0, Asm + c1 * 8);
        gl_lds16(Bb + off0 + k0, Bsm + c0 * 8);
        gl_lds16(Bb + off1 + k0, Bsm + c1 * 8);
        __syncthreads();   // drains vmcnt(0) then barrier (compiler-enforced)
        short8 af[4], bg[4];
#pragma unroll
        for (int i = 0; i < 4; ++i) af[i] = *(const short8*)(aP + i * 512);
#pragma unroll
        for (int j = 0; j < 4; ++j) bg[j] = *(const short8*)(bP + j * 512);
#pragma unroll
        for (int i = 0; i < 4; ++i)
#pragma unroll
            for (int j = 0; j < 4; ++j)
                acc[i][j] = __builtin_amdgcn_mfma_f32_16x16x32_bf16(
                    af[i], bg[j], acc[i][j], 0, 0, 0);
    }

    // C/D layout: col = lane&15, row = quad*4 + reg  [m89/m91 verified]
    unsigned short* Cb = C + (size_t)b * sC + (size_t)(i0 + wr) * N + j0 + wc;
#pragma unroll
    for (int i = 0; i < 4; ++i)
#pragma unroll
        for (int j = 0; j < 4; ++j)
#pragma unroll
            for (int r = 0; r < 4; ++r)
                Cb[(size_t)(i * 16 + quad * 4 + r) * N + j * 16 + l15] =
                    f2bf(acc[i][j][r]);
}

// ---------------------------------------------------------------------------
// Fused beta + pooled
// ---------------------------------------------------------------------------
__global__ __launch_bounds__(256) void pool_kernel(
    const float* __restrict__ mainp, const unsigned short* __restrict__ Aout,
    const float* __restrict__ w, float* __restrict__ out) {
    const int b     = blockIdx.y;
    const int chunk = blockIdx.x;
    const int wave  = threadIdx.x >> 6, lane = threadIdx.x & 63;
    float w1[12], w2[12], ps[12], pm[12];
#pragma unroll
    for (int s = 0; s < 12; ++s) {
        w1[s] = w[s * 64 + lane];
        w2[s] = w[kD + s * 64 + lane];
        ps[s] = 0.f; pm[s] = 0.f;
    }
    for (int rr = 0; rr < 16; ++rr) {
        const int row = chunk * 64 + rr * 4 + wave;
        const float* mr = mainp + ((size_t)b * kLM + row) * kD;
        const unsigned short* ar = Aout + ((size_t)b * kLM + row) * kD;
        float sv[12], mv[12], acc = 0.f;
#pragma unroll
        for (int s = 0; s < 12; ++s) {
            float m_ = mr[s * 64 + lane];
            float a_ = bf2f(ar[s * 64 + lane]);
            sv[s] = m_ - a_;
            mv[s] = m_ * a_;
            acc += sv[s] * w1[s] + mv[s] * w2[s];
        }
#pragma unroll
        for (int off = 32; off; off >>= 1) acc += __shfl_xor(acc, off);
#pragma unroll
        for (int s = 0; s < 12; ++s) { ps[s] += acc * sv[s]; pm[s] += acc * mv[s]; }
    }
    float* ob = out + (size_t)b * 2 * kD;
#pragma unroll
    for (int s = 0; s < 12; ++s) {
        atomicAdd(&ob[s * 64 + lane], ps[s]);
        atomicAdd(&ob[kD + s * 64 + lane], pm[s]);
    }
}

extern "C" void kernel_launch(void* const* d_in, const int* in_sizes, int n_in,
                              void* d_out, int out_size, void* d_ws, size_t ws_size,
                              hipStream_t stream) {
    const float* mainp = (const float*)d_in[0];  // (B, LM, D)
    const float* x     = (const float*)d_in[1];  // (B, LX, D)
    const float* W     = (const float*)d_in[2];  // (D, D)
    const float* w     = (const float*)d_in[3];  // (2D, 1)
    float* out = (float*)d_out;                  // (B, 2D)

    char* p = (char*)d_ws;
    unsigned short* xT    = (unsigned short*)p; p += (size_t)kB * kD * kLX * 2;
    unsigned short* mainb = (unsigned short*)p; p += (size_t)kB * kLM * kD * 2;
    unsigned short* Wb    = (unsigned short*)p; p += (size_t)kD * kD * 2;
    unsigned short* G     = (unsigned short*)p; p += (size_t)kB * kD * kD * 2;
    unsigned short* Mt    = (unsigned short*)p; p += (size_t)kB * kD * kD * 2;
    unsigned short* Ao    = (unsigned short*)p; p += (size_t)kB * kLM * kD * 2;

    hipMemsetAsync(out, 0, (size_t)kB * 2 * kD * sizeof(float), stream);

    transpose_cvt_kernel<<<dim3(kLX / 64, kD / 64, kB), 256, 0, stream>>>(x, xT);
    {
        int n4 = kB * kLM * kD / 4;
        cvt_bf16_kernel<<<(n4 + 255) / 256, 256, 0, stream>>>(mainp, mainb, n4);
        n4 = kD * kD / 4;
        cvt_bf16_kernel<<<(n4 + 255) / 256, 256, 0, stream>>>(W, Wb, n4);
    }
    // G[b] = xT[b] @ xT[b]^T  (= x^T x, symmetric)
    gemm_nt_bf16_kernel<<<dim3(kD / 128, kD / 128, kB), 256, 0, stream>>>(
        xT, xT, G, kD, kD, kLX, (long)kD * kLX, (long)kD * kLX, (long)kD * kD);
    // Mt[b] = G[b] @ W^T   (= (W G)^T since G symmetric)
    gemm_nt_bf16_kernel<<<dim3(kD / 128, kD / 128, kB), 256, 0, stream>>>(
        G, Wb, Mt, kD, kD, kD, (long)kD * kD, 0L, (long)kD * kD);
    // A[b] = main[b] @ Mt[b]^T
    gemm_nt_bf16_kernel<<<dim3(kLM / 128, kD / 128, kB), 256, 0, stream>>>(
        mainb, Mt, Ao, kLM, kD, kD, (long)kLM * kD, (long)kD * kD, (long)kLM * kD);
    pool_kernel<<<dim3(kLM / 64, kB), 256, 0, stream>>>(mainp, Ao, w, out);
}